// Round 16
// baseline (72.622 us; speedup 1.0000x reference)
//
#include <hip/hip_runtime.h>
#include <hip/hip_bf16.h>

// ---------------------------------------------------------------------------
// Metric_Loss: two fused (X X^T/128 -> exp(1+.) -> row-sum) passes + pair combine.
// B=8192, E=128, P=4096.  Output: scalar f32 = metric_tt + metric_st.
//
// Round 16: N-split waves on the R15 zero-tail skeleton. Wave w owns the full
// 64 rows x 16 cols [w*16, w*16+16) of each tile: B-fragment read ONCE per
// block (8 ds_read_b128/tile vs 16 -- no wr-pair duplication), col atomics
// halved. A-frags = 4 m-frags (32 VGPR) hoisted once; MFMA+exp2 epilogue in
// two m-halves to cap live registers (~76 < 84 budget at (256,6)).
// Everything else identical to R15: MX-fp8 16x16x128, 2-phase counted-vmcnt,
// NHS=6 zero-tail grid (1536 blocks = 6/CU), symmetry wrap-pairing,
// exp2 pre-scale sqrt(log2e/128), exact-f32 finalize.
//
// ws layout:
//   [0, 1MB)        Xt fp8    [8192][128]   scaled by sqrt(log2e/128)
//   [1MB, 2MB)      Xm fp8    [8192][128]   (mixed: even=text, odd=shape[r>>1])
//   [2MB, 2MB+64KB) R f32     [2][8192]     row sums of exp(1+D)
// ---------------------------------------------------------------------------

#define B_ROWS 8192
#define E_COLS 128
#define P_PAIRS 4096
#define NSTRIP 128              // 64-row strips
#define NHS 6                   // h-splits per strip (zero-tail: 1536 blocks)

using f32x4 = __attribute__((ext_vector_type(4))) float;
using i32x8 = __attribute__((ext_vector_type(8))) int;

// sqrt(log2(e)/128): MFMA yields acc = D*log2(e); exp(1+D) = e * exp2(acc)
#define BF_SCALE 0.106164482742544f
#define EULER    2.718281828459045f
#define SCALE1   0x7f            // E8M0 exponent 127 -> 2^0 (unit scale)

__device__ __forceinline__ unsigned pk4_fp8(float a, float b, float c, float d) {
    unsigned v = 0;
    v = __builtin_amdgcn_cvt_pk_fp8_f32(a * BF_SCALE, b * BF_SCALE, v, false);
    v = __builtin_amdgcn_cvt_pk_fp8_f32(c * BF_SCALE, d * BF_SCALE, v, true);
    return v;
}

__device__ __forceinline__ int lds_off(int row, int k0) {
    return (row << 7) + (k0 ^ ((row & 7) << 4));
}

// K=128 fragment from swizzled LDS: 32 contiguous fp8 at (row, k32).
__device__ __forceinline__ i32x8 load_frag32(const char* base, int row, int k32) {
    union { i32x8 v; int4 h[2]; } u;
    u.h[0] = *(const int4*)(base + lds_off(row, k32));
    u.h[1] = *(const int4*)(base + lds_off(row, k32 + 16));
    return u.v;
}

// Stage one 64x128 fp8 tile (8KB): 2 iters of 256 threads x 16B.
__device__ __forceinline__ void stage8k(const char* gsrc, char* ldst, int tid) {
#pragma unroll
    for (int it = 0; it < 2; ++it) {
        int L   = it * 4096 + tid * 16;
        int row = L >> 7;
        int cb  = L & 127;
        int src = (row << 7) + (cb ^ ((row & 7) << 4));
        __builtin_amdgcn_global_load_lds(
            (const __attribute__((address_space(1))) void*)(gsrc + src),
            (__attribute__((address_space(3))) void*)(ldst + L), 16, 0, 0);
    }
}

// --------------------------- conversion kernel -----------------------------
__global__ void convert_kernel(const float* __restrict__ text,
                               const float* __restrict__ shape,
                               unsigned* __restrict__ Xt,
                               unsigned* __restrict__ Xm,
                               float* __restrict__ R,
                               float* __restrict__ out) {
    int idx = blockIdx.x * blockDim.x + threadIdx.x;     // 4 elements per thread
    if (idx >= B_ROWS * E_COLS / 4) return;
    if (idx < 4096) {                                    // zero R (2*8192 f32)
        float4 z; z.x = z.y = z.z = z.w = 0.f;
        ((float4*)R)[idx] = z;
    }
    if (idx == 0) *out = 0.f;
    int e = idx * 4;
    float4 t = *(const float4*)(text + e);
    unsigned tp = pk4_fp8(t.x, t.y, t.z, t.w);
    Xt[idx] = tp;
    int row = e >> 7;
    if (row & 1) {
        int col = e & 127;
        float4 s = *(const float4*)(shape + (row >> 1) * E_COLS + col);
        Xm[idx] = pk4_fp8(s.x, s.y, s.z, s.w);
    } else {
        Xm[idx] = tp;
    }
}

// --------------------------- fused GEMM + rowsum (MX-fp8, N-split) ---------
// Block = (strip bm in 0..127, split h in 0..5, layer l). Strip = 64 A-rows.
// h -> distances t = h+1 + 6k (<=63): h<3 -> 11 tiles, h>=3 -> 10.
// h==3 adds the diagonal (from buf0); h==4, bm<64 appends t=64 as idx==10.
// Wave w computes rows 0..63 x cols [w*16, w*16+16) of each 64x64 tile.
__launch_bounds__(256, 6)
__global__ void gemm_rowsum_kernel(const unsigned char* __restrict__ Xt,
                                   const unsigned char* __restrict__ Xm,
                                   float* __restrict__ R) {
    const int bm = blockIdx.x, h = blockIdx.y, l = blockIdx.z;
    const char* gX = (const char*)(l ? Xm : Xt);

    __shared__ __align__(16) char buf0[64 * 128];
    __shared__ __align__(16) char buf1[64 * 128];
    const int tid = threadIdx.x;

    const int t0 = h + 1;
    int N = (h < 3) ? 11 : 10;
    if (h == 4 && bm < 64) N = 11;               // idx==10 -> t=64

    auto tf = [&](int i) -> int { return (h == 4 && i == 10) ? 64 : (t0 + 6 * i); };

    // ---- prologue: stage A -> buf0, first B -> buf1 ----
    stage8k(gX + (size_t)bm * 8192, buf0, tid);
    stage8k(gX + (size_t)((bm + tf(0)) & 127) * 8192, buf1, tid);
    asm volatile("s_waitcnt vmcnt(2)" ::: "memory");     // A landed
    __builtin_amdgcn_s_barrier();

    const int lane = tid & 63;
    const int w    = tid >> 6;
    const int rB0  = w * 16 + (lane & 15);       // wave's B-row (= output col)
    const int rA0  = lane & 15;                  // A-row base (m*16 added)
    const int k32  = (lane >> 4) * 32;           // byte offset of lane's K-slice

    // ---- hoist A fragments (4 m-frags, full K=128 each) ----
    i32x8 afr[4];
#pragma unroll
    for (int m = 0; m < 4; ++m)
        afr[m] = load_frag32(buf0, rA0 + m * 16, k32);

    float s_r[4][4] = {{0.f}};                   // row partials [m][j], wave's 16 cols

    // ---- diagonal tile (h==3): B-frag also from buf0; rows only ----
    if (h == 3) {
        i32x8 dbf = load_frag32(buf0, rB0, k32);
#pragma unroll
        for (int mh = 0; mh < 2; ++mh) {
            f32x4 a0 = {}, a1 = {};
            a0 = __builtin_amdgcn_mfma_scale_f32_16x16x128_f8f6f4(
                afr[2 * mh + 0], dbf, a0, 0, 0, 0, SCALE1, 0, SCALE1);
            a1 = __builtin_amdgcn_mfma_scale_f32_16x16x128_f8f6f4(
                afr[2 * mh + 1], dbf, a1, 0, 0, 0, SCALE1, 0, SCALE1);
#pragma unroll
            for (int j = 0; j < 4; ++j) {
                s_r[2 * mh + 0][j] += __builtin_amdgcn_exp2f(a0[j]);
                s_r[2 * mh + 1][j] += __builtin_amdgcn_exp2f(a1[j]);
            }
        }
    }

    // ---- all buf0 reads done before it becomes a B buffer ----
    asm volatile("s_waitcnt lgkmcnt(0)" ::: "memory");
    __builtin_amdgcn_s_barrier();

    // ---- 2-phase pipelined loop over off-diagonal tiles ----
    int cur = 1;                                 // current B buffer: 1 -> buf1
    for (int idx = 0; idx < N; ++idx) {
        const bool hasnext = (idx + 1 < N);
        if (hasnext)
            stage8k(gX + (size_t)((bm + tf(idx + 1)) & 127) * 8192,
                    cur ? buf0 : buf1, tid);

        if (hasnext) { asm volatile("s_waitcnt vmcnt(2)" ::: "memory"); }
        else         { asm volatile("s_waitcnt vmcnt(0)" ::: "memory"); }
        __builtin_amdgcn_s_barrier();            // cur buffer staged (all waves)

        const char* lsrc = cur ? buf1 : buf0;
        i32x8 bfr = load_frag32(lsrc, rB0, k32); // ONE frag per wave per tile

        float sc = 0.f;
#pragma unroll
        for (int mh = 0; mh < 2; ++mh) {
            f32x4 a0 = {}, a1 = {};
            __builtin_amdgcn_s_setprio(1);
            a0 = __builtin_amdgcn_mfma_scale_f32_16x16x128_f8f6f4(
                afr[2 * mh + 0], bfr, a0, 0, 0, 0, SCALE1, 0, SCALE1);
            a1 = __builtin_amdgcn_mfma_scale_f32_16x16x128_f8f6f4(
                afr[2 * mh + 1], bfr, a1, 0, 0, 0, SCALE1, 0, SCALE1);
            __builtin_amdgcn_s_setprio(0);
#pragma unroll
            for (int j = 0; j < 4; ++j) {
                float e0 = __builtin_amdgcn_exp2f(a0[j]);
                float e1 = __builtin_amdgcn_exp2f(a1[j]);
                s_r[2 * mh + 0][j] += e0;
                s_r[2 * mh + 1][j] += e1;
                sc += e0 + e1;
            }
        }

        asm volatile("s_waitcnt lgkmcnt(0)" ::: "memory");
        __builtin_amdgcn_s_barrier();            // cur reads done -> overwritable

        // ---- col sums: reduce over 4 k-groups, 16 exclusive cols ----
        const int bn = (bm + tf(idx)) & 127;
        sc += __shfl_xor(sc, 16, 64);
        sc += __shfl_xor(sc, 32, 64);
        if (lane < 16) {
            int gcol = bn * 64 + w * 16 + lane;
            atomicAdd(&R[l * B_ROWS + gcol], EULER * sc);
        }
        cur ^= 1;
    }

    // ---- row reduction: sum wave's 16-col partials (lanes xor 1,2,4,8) ----
#pragma unroll
    for (int m = 0; m < 4; ++m)
#pragma unroll
        for (int j = 0; j < 4; ++j) {
            float v = s_r[m][j];
            v += __shfl_xor(v, 1, 64);
            v += __shfl_xor(v, 2, 64);
            v += __shfl_xor(v, 4, 64);
            v += __shfl_xor(v, 8, 64);
            if ((lane & 15) == 0) {
                int grow = bm * 64 + m * 16 + (lane >> 4) * 4 + j;
                atomicAdd(&R[l * B_ROWS + grow], EULER * v);
            }
        }
}

// --------------------------- finalize --------------------------------------
__global__ void finalize_kernel(const float* __restrict__ text,
                                const float* __restrict__ shape,
                                const float* __restrict__ R,
                                float* __restrict__ out) {
    const int tid = threadIdx.x;
    const int lane = tid & 63;
    const int w = tid >> 6;
    const float inv128 = 0.0078125f;
    float accum = 0.f;

    for (int task = blockIdx.x * 4 + w; task < 2 * P_PAIRS; task += 1024) {
        int l = task >> 12;
        int p = task & (P_PAIRS - 1);
        const float* a = text + (2 * p) * E_COLS;            // even row: text
        const float* b = l ? (shape + p * E_COLS) : (text + (2 * p + 1) * E_COLS);
        float2 av = *(const float2*)(a + lane * 2);
        float2 bv = *(const float2*)(b + lane * 2);
        float dii = av.x * av.x + av.y * av.y;
        float djj = bv.x * bv.x + bv.y * bv.y;
        float dij = av.x * bv.x + av.y * bv.y;
#pragma unroll
        for (int sh = 1; sh < 64; sh <<= 1) {
            dii += __shfl_xor(dii, sh, 64);
            djj += __shfl_xor(djj, sh, 64);
            dij += __shfl_xor(dij, sh, 64);
        }
        if (lane == 0) {
            float Dii = dii * inv128, Djj = djj * inv128, Dij = dij * inv128;
            float S = R[l * B_ROWS + 2 * p] + R[l * B_ROWS + 2 * p + 1]
                    - (__expf(1.f + Dii) + 2.f * __expf(1.f + Dij) + __expf(1.f + Djj));
            float J = __logf(S) - Dij;
            accum += 0.5f * J * J * (1.0f / (float)P_PAIRS);
        }
    }

    __shared__ float red[4];
    if (lane == 0) red[w] = accum;
    __syncthreads();
    if (tid == 0) atomicAdd(out, red[0] + red[1] + red[2] + red[3]);
}

// --------------------------- launch ----------------------------------------
extern "C" void kernel_launch(void* const* d_in, const int* in_sizes, int n_in,
                              void* d_out, int out_size, void* d_ws, size_t ws_size,
                              hipStream_t stream) {
    const float* text  = (const float*)d_in[0];
    const float* shape = (const float*)d_in[1];
    float* out = (float*)d_out;
    char* ws = (char*)d_ws;

    unsigned char* Xt = (unsigned char*)ws;
    unsigned char* Xm = (unsigned char*)(ws + 1u * 1024u * 1024u);
    float* R = (float*)(ws + 2u * 1024u * 1024u);

    convert_kernel<<<(B_ROWS * E_COLS / 4 + 255) / 256, 256, 0, stream>>>(
        text, shape, (unsigned*)Xt, (unsigned*)Xm, R, out);

    dim3 grid(NSTRIP, NHS, 2);                   // 128 strips x 6 splits x 2 layers
    gemm_rowsum_kernel<<<grid, 256, 0, stream>>>(Xt, Xm, R);

    finalize_kernel<<<256, 256, 0, stream>>>(text, shape, R, out);
}

// Round 17
// 43.178 us; speedup vs baseline: 1.6819x; 1.6819x over previous
//
#include <hip/hip_runtime.h>
#include <hip/hip_bf16.h>

// ---------------------------------------------------------------------------
// Metric_Loss: two fused (X X^T/128 -> exp(1+.) -> row-sum) passes + pair combine.
// B=8192, E=128, P=4096.  Output: scalar f32 = metric_tt + metric_st.
//
// Round 17: R15 skeleton (quadrant waves, NHS=6 zero-tail, MX-fp8 16x16x128,
// register-feasible afr[2]/bfr[2]/acc[2][2]) with ONE barrier per tile:
//  - ring-3 LDS banks (3 x 8KB = 24KB -> residency stays 6 blocks/CU)
//  - A-frags + diagonal B-frags straight from global (1MB, L2-resident);
//    no A-buffer, no prologue full-drain barrier pair
//  - per-tile: vmcnt(vm) -> s_barrier -> stage(idx+2) -> ds_read -> MFMA ->
//    exp2 -> shuffle+atomic -> lgkmcnt(0).  vm = min(idx,2) + (idx+1<N ? 2:0)
//    exactly covers the {2 stage loads + 1 atomic}/iter VMEM stream.
//  - fully unrolled (N in {10,11}) -> ring indices & vmcnt literals static.
//
// ws layout:
//   [0, 1MB)        Xt fp8    [8192][128]   scaled by sqrt(log2e/128)
//   [1MB, 2MB)      Xm fp8    [8192][128]   (mixed: even=text, odd=shape[r>>1])
//   [2MB, 2MB+64KB) R f32     [2][8192]     row sums of exp(1+D)
// ---------------------------------------------------------------------------

#define B_ROWS 8192
#define E_COLS 128
#define P_PAIRS 4096
#define NSTRIP 128              // 64-row strips
#define NHS 6                   // h-splits per strip (zero-tail: 1536 blocks)

using f32x4 = __attribute__((ext_vector_type(4))) float;
using i32x8 = __attribute__((ext_vector_type(8))) int;

// sqrt(log2(e)/128): MFMA yields acc = D*log2(e); exp(1+D) = e * exp2(acc)
#define BF_SCALE 0.106164482742544f
#define EULER    2.718281828459045f
#define SCALE1   0x7f            // E8M0 exponent 127 -> 2^0 (unit scale)

__device__ __forceinline__ unsigned pk4_fp8(float a, float b, float c, float d) {
    unsigned v = 0;
    v = __builtin_amdgcn_cvt_pk_fp8_f32(a * BF_SCALE, b * BF_SCALE, v, false);
    v = __builtin_amdgcn_cvt_pk_fp8_f32(c * BF_SCALE, d * BF_SCALE, v, true);
    return v;
}

__device__ __forceinline__ int lds_off(int row, int k0) {
    return (row << 7) + (k0 ^ ((row & 7) << 4));
}

// K=128 fragment from swizzled LDS: 32 contiguous fp8 at (row, k32).
__device__ __forceinline__ i32x8 load_frag32(const char* base, int row, int k32) {
    union { i32x8 v; int4 h[2]; } u;
    u.h[0] = *(const int4*)(base + lds_off(row, k32));
    u.h[1] = *(const int4*)(base + lds_off(row, k32 + 16));
    return u.v;
}

// K=128 fragment straight from global (row-major, unswizzled).
__device__ __forceinline__ i32x8 load_frag32_g(const char* rowbase, int k32) {
    union { i32x8 v; int4 h[2]; } u;
    u.h[0] = *(const int4*)(rowbase + k32);
    u.h[1] = *(const int4*)(rowbase + k32 + 16);
    return u.v;
}

// Stage one 64x128 fp8 tile (8KB): 2 iters of 256 threads x 16B.
__device__ __forceinline__ void stage8k(const char* gsrc, char* ldst, int tid) {
#pragma unroll
    for (int it = 0; it < 2; ++it) {
        int L   = it * 4096 + tid * 16;
        int row = L >> 7;
        int cb  = L & 127;
        int src = (row << 7) + (cb ^ ((row & 7) << 4));
        __builtin_amdgcn_global_load_lds(
            (const __attribute__((address_space(1))) void*)(gsrc + src),
            (__attribute__((address_space(3))) void*)(ldst + L), 16, 0, 0);
    }
}

// --------------------------- conversion kernel -----------------------------
__global__ void convert_kernel(const float* __restrict__ text,
                               const float* __restrict__ shape,
                               unsigned* __restrict__ Xt,
                               unsigned* __restrict__ Xm,
                               float* __restrict__ R,
                               float* __restrict__ out) {
    int idx = blockIdx.x * blockDim.x + threadIdx.x;     // 4 elements per thread
    if (idx >= B_ROWS * E_COLS / 4) return;
    if (idx < 4096) {                                    // zero R (2*8192 f32)
        float4 z; z.x = z.y = z.z = z.w = 0.f;
        ((float4*)R)[idx] = z;
    }
    if (idx == 0) *out = 0.f;
    int e = idx * 4;
    float4 t = *(const float4*)(text + e);
    unsigned tp = pk4_fp8(t.x, t.y, t.z, t.w);
    Xt[idx] = tp;
    int row = e >> 7;
    if (row & 1) {
        int col = e & 127;
        float4 s = *(const float4*)(shape + (row >> 1) * E_COLS + col);
        Xm[idx] = pk4_fp8(s.x, s.y, s.z, s.w);
    } else {
        Xm[idx] = tp;
    }
}

// --------------------------- fused GEMM + rowsum (MX-fp8, 1-barrier) -------
// Block = (strip bm in 0..127, split h in 0..5, layer l). Strip = 64 A-rows.
// h -> distances t = h+1 + 6k (<=63): h<3 -> 11 tiles, h>=3 -> 10.
// h==3 adds the diagonal (from global); h==4, bm<64 appends t=64 as idx==10.
__launch_bounds__(256, 6)
__global__ void gemm_rowsum_kernel(const unsigned char* __restrict__ Xt,
                                   const unsigned char* __restrict__ Xm,
                                   float* __restrict__ R) {
    const int bm = blockIdx.x, h = blockIdx.y, l = blockIdx.z;
    const char* gX = (const char*)(l ? Xm : Xt);

    __shared__ __align__(16) char bufs[3][64 * 128];     // 24KB ring
    const int tid = threadIdx.x;

    const int t0 = h + 1;
    int N = (h < 3) ? 11 : 10;
    if (h == 4 && bm < 64) N = 11;               // idx==10 -> t=64

    auto tf = [&](int i) -> int { return (h == 4 && i == 10) ? 64 : (t0 + 6 * i); };

    const int lane = tid & 63;
    const int w  = tid >> 6;
    const int wr = w >> 1, wc = w & 1;
    const int rA0 = wr * 32 + (lane & 15);
    const int rB0 = wc * 32 + (lane & 15);
    const int k32 = (lane >> 4) * 32;            // byte offset of lane's K-slice

    // ---- prologue: afr (+diag) from global FIRST, then stage tiles 0,1 ----
    const char* Ag = gX + (size_t)bm * 8192;
    i32x8 afr[2];
    afr[0] = load_frag32_g(Ag + (size_t)rA0 * 128, k32);
    afr[1] = load_frag32_g(Ag + (size_t)(rA0 + 16) * 128, k32);

    i32x8 db0 = {}, db1 = {};
    if (h == 3) {
        db0 = load_frag32_g(Ag + (size_t)rB0 * 128, k32);
        db1 = load_frag32_g(Ag + (size_t)(rB0 + 16) * 128, k32);
    }

    stage8k(gX + (size_t)((bm + tf(0)) & 127) * 8192, bufs[0], tid);
    stage8k(gX + (size_t)((bm + tf(1)) & 127) * 8192, bufs[1], tid);

    // afr (+diag) are the OLDEST loads; 4 stage loads may stay in flight
    asm volatile("s_waitcnt vmcnt(4)" ::: "memory");

    float s_r[2][4] = {{0.f}};                   // persistent row partials [m][j]

    // ---- diagonal tile (h==3): all-register; rows only ----
    if (h == 3) {
        f32x4 acc[2][2] = {};
        acc[0][0] = __builtin_amdgcn_mfma_scale_f32_16x16x128_f8f6f4(
            afr[0], db0, acc[0][0], 0, 0, 0, SCALE1, 0, SCALE1);
        acc[0][1] = __builtin_amdgcn_mfma_scale_f32_16x16x128_f8f6f4(
            afr[0], db1, acc[0][1], 0, 0, 0, SCALE1, 0, SCALE1);
        acc[1][0] = __builtin_amdgcn_mfma_scale_f32_16x16x128_f8f6f4(
            afr[1], db0, acc[1][0], 0, 0, 0, SCALE1, 0, SCALE1);
        acc[1][1] = __builtin_amdgcn_mfma_scale_f32_16x16x128_f8f6f4(
            afr[1], db1, acc[1][1], 0, 0, 0, SCALE1, 0, SCALE1);
#pragma unroll
        for (int m = 0; m < 2; ++m)
#pragma unroll
            for (int n = 0; n < 2; ++n)
#pragma unroll
                for (int j = 0; j < 4; ++j)
                    s_r[m][j] += __builtin_amdgcn_exp2f(acc[m][n][j]);
    }

    // ---- main loop: ONE barrier per tile, ring-3, depth-2 prefetch ----
#pragma unroll
    for (int idx = 0; idx < 11; ++idx) {
        if (idx >= N) break;

        // exact VMEM accounting: stream = {2 stage + 1 atomic}/iter.
        // newer-than-stage(idx) entries: min(idx,2) atomics + 2 stages if idx+1<N.
        const int vm = ((idx < 2) ? idx : 2) + ((idx + 1 < N) ? 2 : 0);
        if (vm == 4)      { asm volatile("s_waitcnt vmcnt(4)" ::: "memory"); }
        else if (vm == 3) { asm volatile("s_waitcnt vmcnt(3)" ::: "memory"); }
        else              { asm volatile("s_waitcnt vmcnt(2)" ::: "memory"); }
        __builtin_amdgcn_s_barrier();            // tile idx landed (all waves);
                                                 // all reads of bufs[(idx+2)%3] done

        if (idx + 2 < N)
            stage8k(gX + (size_t)((bm + tf(idx + 2)) & 127) * 8192,
                    bufs[(idx + 2) % 3], tid);

        const char* lsrc = bufs[idx % 3];
        i32x8 bfr[2];
        bfr[0] = load_frag32(lsrc, rB0, k32);
        bfr[1] = load_frag32(lsrc, rB0 + 16, k32);

        f32x4 acc[2][2] = {};
        __builtin_amdgcn_s_setprio(1);
        acc[0][0] = __builtin_amdgcn_mfma_scale_f32_16x16x128_f8f6f4(
            afr[0], bfr[0], acc[0][0], 0, 0, 0, SCALE1, 0, SCALE1);
        acc[0][1] = __builtin_amdgcn_mfma_scale_f32_16x16x128_f8f6f4(
            afr[0], bfr[1], acc[0][1], 0, 0, 0, SCALE1, 0, SCALE1);
        acc[1][0] = __builtin_amdgcn_mfma_scale_f32_16x16x128_f8f6f4(
            afr[1], bfr[0], acc[1][0], 0, 0, 0, SCALE1, 0, SCALE1);
        acc[1][1] = __builtin_amdgcn_mfma_scale_f32_16x16x128_f8f6f4(
            afr[1], bfr[1], acc[1][1], 0, 0, 0, SCALE1, 0, SCALE1);
        __builtin_amdgcn_s_setprio(0);

        // ---- epilogue: rows -> regs, cols -> shuffle + atomic (1 VMEM) ----
        const int bn = (bm + tf(idx)) & 127;
        float s_c[2] = {0.f, 0.f};
#pragma unroll
        for (int m = 0; m < 2; ++m)
#pragma unroll
            for (int n = 0; n < 2; ++n)
#pragma unroll
                for (int j = 0; j < 4; ++j) {
                    float e2 = __builtin_amdgcn_exp2f(acc[m][n][j]);
                    s_r[m][j] += e2;
                    s_c[n] += e2;
                }
        float v0 = s_c[0] + __shfl_xor(s_c[0], 16, 64);
        v0 += __shfl_xor(v0, 32, 64);
        float v1 = s_c[1] + __shfl_xor(s_c[1], 16, 64);
        v1 += __shfl_xor(v1, 32, 64);
        if (lane < 32) {                          // 1 atomic inst per wave
            int nn   = lane >> 4;                 // 0 -> s_c[0], 1 -> s_c[1]
            float vv = nn ? v1 : v0;
            int gcol = bn * 64 + wc * 32 + nn * 16 + (lane & 15);
            atomicAdd(&R[l * B_ROWS + gcol], EULER * vv);
        }

        asm volatile("s_waitcnt lgkmcnt(0)" ::: "memory");  // my ds ops done
    }

    // ---- final row reduction (once per block) ----
#pragma unroll
    for (int m = 0; m < 2; ++m)
#pragma unroll
        for (int j = 0; j < 4; ++j) {
            float v = s_r[m][j];
            v += __shfl_xor(v, 1, 64);
            v += __shfl_xor(v, 2, 64);
            v += __shfl_xor(v, 4, 64);
            v += __shfl_xor(v, 8, 64);
            if ((lane & 15) == 0) {
                int grow = bm * 64 + wr * 32 + m * 16 + (lane >> 4) * 4 + j;
                atomicAdd(&R[l * B_ROWS + grow], EULER * v);
            }
        }
}

// --------------------------- finalize --------------------------------------
__global__ void finalize_kernel(const float* __restrict__ text,
                                const float* __restrict__ shape,
                                const float* __restrict__ R,
                                float* __restrict__ out) {
    const int tid = threadIdx.x;
    const int lane = tid & 63;
    const int w = tid >> 6;
    const float inv128 = 0.0078125f;
    float accum = 0.f;

    for (int task = blockIdx.x * 4 + w; task < 2 * P_PAIRS; task += 1024) {
        int l = task >> 12;
        int p = task & (P_PAIRS - 1);
        const float* a = text + (2 * p) * E_COLS;            // even row: text
        const float* b = l ? (shape + p * E_COLS) : (text + (2 * p + 1) * E_COLS);
        float2 av = *(const float2*)(a + lane * 2);
        float2 bv = *(const float2*)(b + lane * 2);
        float dii = av.x * av.x + av.y * av.y;
        float djj = bv.x * bv.x + bv.y * bv.y;
        float dij = av.x * bv.x + av.y * bv.y;
#pragma unroll
        for (int sh = 1; sh < 64; sh <<= 1) {
            dii += __shfl_xor(dii, sh, 64);
            djj += __shfl_xor(djj, sh, 64);
            dij += __shfl_xor(dij, sh, 64);
        }
        if (lane == 0) {
            float Dii = dii * inv128, Djj = djj * inv128, Dij = dij * inv128;
            float S = R[l * B_ROWS + 2 * p] + R[l * B_ROWS + 2 * p + 1]
                    - (__expf(1.f + Dii) + 2.f * __expf(1.f + Dij) + __expf(1.f + Djj));
            float J = __logf(S) - Dij;
            accum += 0.5f * J * J * (1.0f / (float)P_PAIRS);
        }
    }

    __shared__ float red[4];
    if (lane == 0) red[w] = accum;
    __syncthreads();
    if (tid == 0) atomicAdd(out, red[0] + red[1] + red[2] + red[3]);
}

// --------------------------- launch ----------------------------------------
extern "C" void kernel_launch(void* const* d_in, const int* in_sizes, int n_in,
                              void* d_out, int out_size, void* d_ws, size_t ws_size,
                              hipStream_t stream) {
    const float* text  = (const float*)d_in[0];
    const float* shape = (const float*)d_in[1];
    float* out = (float*)d_out;
    char* ws = (char*)d_ws;

    unsigned char* Xt = (unsigned char*)ws;
    unsigned char* Xm = (unsigned char*)(ws + 1u * 1024u * 1024u);
    float* R = (float*)(ws + 2u * 1024u * 1024u);

    convert_kernel<<<(B_ROWS * E_COLS / 4 + 255) / 256, 256, 0, stream>>>(
        text, shape, (unsigned*)Xt, (unsigned*)Xm, R, out);

    dim3 grid(NSTRIP, NHS, 2);                   // 128 strips x 6 splits x 2 layers
    gemm_rowsum_kernel<<<grid, 256, 0, stream>>>(Xt, Xm, R);

    finalize_kernel<<<256, 256, 0, stream>>>(text, shape, R, out);
}

// Round 18
// 39.628 us; speedup vs baseline: 1.8326x; 1.0896x over previous
//
#include <hip/hip_runtime.h>
#include <hip/hip_bf16.h>

// ---------------------------------------------------------------------------
// Metric_Loss: two fused (X X^T/128 -> exp(1+.) -> row-sum) passes + pair combine.
// B=8192, E=128, P=4096.  Output: scalar f32 = metric_tt + metric_st.
//
// Round 18: NHS=7 zero-tail (1792 blocks = exactly 7/CU, 28 waves/CU) on the
// R15 skeleton. Distances t = h+1+7k tile exactly: 7 splits x 9 = 63; diag
// at h==3 (from buf0); t=64 appended to h==0, bm<64 (idx==9). To fit the
// (256,7) VGPR budget (73), the per-tile epilogue runs one n-half at a time
// (bfr-n -> 2 MFMA -> exp2), halving peak live tuples vs R15. Everything
// else identical: MX-fp8 16x16x128, 2-phase counted-vmcnt, 16KB LDS,
// exp2 pre-scale sqrt(log2e/128), exact-f32 finalize.
//
// ws layout:
//   [0, 1MB)        Xt fp8    [8192][128]   scaled by sqrt(log2e/128)
//   [1MB, 2MB)      Xm fp8    [8192][128]   (mixed: even=text, odd=shape[r>>1])
//   [2MB, 2MB+64KB) R f32     [2][8192]     row sums of exp(1+D)
// ---------------------------------------------------------------------------

#define B_ROWS 8192
#define E_COLS 128
#define P_PAIRS 4096
#define NSTRIP 128              // 64-row strips
#define NHS 7                   // h-splits per strip (zero-tail: 1792 blocks)

using f32x4 = __attribute__((ext_vector_type(4))) float;
using i32x8 = __attribute__((ext_vector_type(8))) int;

// sqrt(log2(e)/128): MFMA yields acc = D*log2(e); exp(1+D) = e * exp2(acc)
#define BF_SCALE 0.106164482742544f
#define EULER    2.718281828459045f
#define SCALE1   0x7f            // E8M0 exponent 127 -> 2^0 (unit scale)

__device__ __forceinline__ unsigned pk4_fp8(float a, float b, float c, float d) {
    unsigned v = 0;
    v = __builtin_amdgcn_cvt_pk_fp8_f32(a * BF_SCALE, b * BF_SCALE, v, false);
    v = __builtin_amdgcn_cvt_pk_fp8_f32(c * BF_SCALE, d * BF_SCALE, v, true);
    return v;
}

__device__ __forceinline__ int lds_off(int row, int k0) {
    return (row << 7) + (k0 ^ ((row & 7) << 4));
}

// K=128 fragment from swizzled LDS: 32 contiguous fp8 at (row, k32).
__device__ __forceinline__ i32x8 load_frag32(const char* base, int row, int k32) {
    union { i32x8 v; int4 h[2]; } u;
    u.h[0] = *(const int4*)(base + lds_off(row, k32));
    u.h[1] = *(const int4*)(base + lds_off(row, k32 + 16));
    return u.v;
}

// Stage one 64x128 fp8 tile (8KB): 2 iters of 256 threads x 16B.
__device__ __forceinline__ void stage8k(const char* gsrc, char* ldst, int tid) {
#pragma unroll
    for (int it = 0; it < 2; ++it) {
        int L   = it * 4096 + tid * 16;
        int row = L >> 7;
        int cb  = L & 127;
        int src = (row << 7) + (cb ^ ((row & 7) << 4));
        __builtin_amdgcn_global_load_lds(
            (const __attribute__((address_space(1))) void*)(gsrc + src),
            (__attribute__((address_space(3))) void*)(ldst + L), 16, 0, 0);
    }
}

// --------------------------- conversion kernel -----------------------------
__global__ void convert_kernel(const float* __restrict__ text,
                               const float* __restrict__ shape,
                               unsigned* __restrict__ Xt,
                               unsigned* __restrict__ Xm,
                               float* __restrict__ R,
                               float* __restrict__ out) {
    int idx = blockIdx.x * blockDim.x + threadIdx.x;     // 4 elements per thread
    if (idx >= B_ROWS * E_COLS / 4) return;
    if (idx < 4096) {                                    // zero R (2*8192 f32)
        float4 z; z.x = z.y = z.z = z.w = 0.f;
        ((float4*)R)[idx] = z;
    }
    if (idx == 0) *out = 0.f;
    int e = idx * 4;
    float4 t = *(const float4*)(text + e);
    unsigned tp = pk4_fp8(t.x, t.y, t.z, t.w);
    Xt[idx] = tp;
    int row = e >> 7;
    if (row & 1) {
        int col = e & 127;
        float4 s = *(const float4*)(shape + (row >> 1) * E_COLS + col);
        Xm[idx] = pk4_fp8(s.x, s.y, s.z, s.w);
    } else {
        Xm[idx] = tp;
    }
}

// --------------------------- fused GEMM + rowsum (MX-fp8) ------------------
// Block = (strip bm in 0..127, split h in 0..6, layer l). Strip = 64 A-rows.
// h -> distances t = h+1 + 7k, k=0..8 (covers t=1..63 exactly once).
// h==3 adds the diagonal (from buf0); h==0, bm<64 appends t=64 as idx==9.
__launch_bounds__(256, 7)
__global__ void gemm_rowsum_kernel(const unsigned char* __restrict__ Xt,
                                   const unsigned char* __restrict__ Xm,
                                   float* __restrict__ R) {
    const int bm = blockIdx.x, h = blockIdx.y, l = blockIdx.z;
    const char* gX = (const char*)(l ? Xm : Xt);

    __shared__ __align__(16) char buf0[64 * 128];
    __shared__ __align__(16) char buf1[64 * 128];
    const int tid = threadIdx.x;

    const int t0 = h + 1;
    int N = 9;
    if (h == 0 && bm < 64) N = 10;               // idx==9 -> t=64

    auto tf = [&](int i) -> int { return (h == 0 && i == 9) ? 64 : (t0 + 7 * i); };

    // ---- prologue: stage A -> buf0, first B -> buf1 ----
    stage8k(gX + (size_t)bm * 8192, buf0, tid);
    stage8k(gX + (size_t)((bm + tf(0)) & 127) * 8192, buf1, tid);
    asm volatile("s_waitcnt vmcnt(2)" ::: "memory");     // A landed
    __builtin_amdgcn_s_barrier();

    const int lane = tid & 63;
    const int w  = tid >> 6;
    const int wr = w >> 1, wc = w & 1;
    const int rA0 = wr * 32 + (lane & 15);
    const int rB0 = wc * 32 + (lane & 15);
    const int k32 = (lane >> 4) * 32;            // byte offset of lane's K-slice

    // ---- hoist A fragments (2 m-frags, full K=128 each) ----
    i32x8 afr[2];
#pragma unroll
    for (int m = 0; m < 2; ++m)
        afr[m] = load_frag32(buf0, rA0 + m * 16, k32);

    float s_r[2][4] = {{0.f}};                   // persistent row partials [m][j]

    // ---- diagonal tile (h==3): B-frags also from buf0; rows only ----
    if (h == 3) {
#pragma unroll
        for (int n = 0; n < 2; ++n) {            // one n-half at a time
            i32x8 bfr = load_frag32(buf0, rB0 + n * 16, k32);
            f32x4 a0 = {}, a1 = {};
            a0 = __builtin_amdgcn_mfma_scale_f32_16x16x128_f8f6f4(
                afr[0], bfr, a0, 0, 0, 0, SCALE1, 0, SCALE1);
            a1 = __builtin_amdgcn_mfma_scale_f32_16x16x128_f8f6f4(
                afr[1], bfr, a1, 0, 0, 0, SCALE1, 0, SCALE1);
#pragma unroll
            for (int j = 0; j < 4; ++j) {
                s_r[0][j] += __builtin_amdgcn_exp2f(a0[j]);
                s_r[1][j] += __builtin_amdgcn_exp2f(a1[j]);
            }
        }
    }

    // ---- all buf0 reads done before it becomes a B buffer ----
    asm volatile("s_waitcnt lgkmcnt(0)" ::: "memory");
    __builtin_amdgcn_s_barrier();

    // ---- 2-phase pipelined loop over off-diagonal tiles ----
    int cur = 1;                                 // current B buffer: 1 -> buf1
    for (int idx = 0; idx < N; ++idx) {
        const bool hasnext = (idx + 1 < N);
        if (hasnext)
            stage8k(gX + (size_t)((bm + tf(idx + 1)) & 127) * 8192,
                    cur ? buf0 : buf1, tid);

        if (hasnext) { asm volatile("s_waitcnt vmcnt(2)" ::: "memory"); }
        else         { asm volatile("s_waitcnt vmcnt(0)" ::: "memory"); }
        __builtin_amdgcn_s_barrier();            // cur buffer staged (all waves)

        const char* lsrc = cur ? buf1 : buf0;
        float s_c[2];
#pragma unroll
        for (int n = 0; n < 2; ++n) {            // one n-half at a time
            i32x8 bfr = load_frag32(lsrc, rB0 + n * 16, k32);
            f32x4 a0 = {}, a1 = {};
            __builtin_amdgcn_s_setprio(1);
            a0 = __builtin_amdgcn_mfma_scale_f32_16x16x128_f8f6f4(
                afr[0], bfr, a0, 0, 0, 0, SCALE1, 0, SCALE1);
            a1 = __builtin_amdgcn_mfma_scale_f32_16x16x128_f8f6f4(
                afr[1], bfr, a1, 0, 0, 0, SCALE1, 0, SCALE1);
            __builtin_amdgcn_s_setprio(0);
            float c = 0.f;
#pragma unroll
            for (int j = 0; j < 4; ++j) {
                float e0 = __builtin_amdgcn_exp2f(a0[j]);
                float e1 = __builtin_amdgcn_exp2f(a1[j]);
                s_r[0][j] += e0;
                s_r[1][j] += e1;
                c += e0 + e1;
            }
            s_c[n] = c;
        }

        asm volatile("s_waitcnt lgkmcnt(0)" ::: "memory");
        __builtin_amdgcn_s_barrier();            // cur reads done -> overwritable

        // ---- col sums -> shuffle + single atomic per wave ----
        const int bn = (bm + tf(idx)) & 127;
        float v0 = s_c[0] + __shfl_xor(s_c[0], 16, 64);
        v0 += __shfl_xor(v0, 32, 64);
        float v1 = s_c[1] + __shfl_xor(s_c[1], 16, 64);
        v1 += __shfl_xor(v1, 32, 64);
        if (lane < 32) {
            int nn   = lane >> 4;
            float vv = nn ? v1 : v0;
            int gcol = bn * 64 + wc * 32 + nn * 16 + (lane & 15);
            atomicAdd(&R[l * B_ROWS + gcol], EULER * vv);
        }
        cur ^= 1;
    }

    // ---- final row reduction (once per block) ----
#pragma unroll
    for (int m = 0; m < 2; ++m)
#pragma unroll
        for (int j = 0; j < 4; ++j) {
            float v = s_r[m][j];
            v += __shfl_xor(v, 1, 64);
            v += __shfl_xor(v, 2, 64);
            v += __shfl_xor(v, 4, 64);
            v += __shfl_xor(v, 8, 64);
            if ((lane & 15) == 0) {
                int grow = bm * 64 + wr * 32 + m * 16 + (lane >> 4) * 4 + j;
                atomicAdd(&R[l * B_ROWS + grow], EULER * v);
            }
        }
}

// --------------------------- finalize --------------------------------------
__global__ void finalize_kernel(const float* __restrict__ text,
                                const float* __restrict__ shape,
                                const float* __restrict__ R,
                                float* __restrict__ out) {
    const int tid = threadIdx.x;
    const int lane = tid & 63;
    const int w = tid >> 6;
    const float inv128 = 0.0078125f;
    float accum = 0.f;

    for (int task = blockIdx.x * 4 + w; task < 2 * P_PAIRS; task += 1024) {
        int l = task >> 12;
        int p = task & (P_PAIRS - 1);
        const float* a = text + (2 * p) * E_COLS;            // even row: text
        const float* b = l ? (shape + p * E_COLS) : (text + (2 * p + 1) * E_COLS);
        float2 av = *(const float2*)(a + lane * 2);
        float2 bv = *(const float2*)(b + lane * 2);
        float dii = av.x * av.x + av.y * av.y;
        float djj = bv.x * bv.x + bv.y * bv.y;
        float dij = av.x * bv.x + av.y * bv.y;
#pragma unroll
        for (int sh = 1; sh < 64; sh <<= 1) {
            dii += __shfl_xor(dii, sh, 64);
            djj += __shfl_xor(djj, sh, 64);
            dij += __shfl_xor(dij, sh, 64);
        }
        if (lane == 0) {
            float Dii = dii * inv128, Djj = djj * inv128, Dij = dij * inv128;
            float S = R[l * B_ROWS + 2 * p] + R[l * B_ROWS + 2 * p + 1]
                    - (__expf(1.f + Dii) + 2.f * __expf(1.f + Dij) + __expf(1.f + Djj));
            float J = __logf(S) - Dij;
            accum += 0.5f * J * J * (1.0f / (float)P_PAIRS);
        }
    }

    __shared__ float red[4];
    if (lane == 0) red[w] = accum;
    __syncthreads();
    if (tid == 0) atomicAdd(out, red[0] + red[1] + red[2] + red[3]);
}

// --------------------------- launch ----------------------------------------
extern "C" void kernel_launch(void* const* d_in, const int* in_sizes, int n_in,
                              void* d_out, int out_size, void* d_ws, size_t ws_size,
                              hipStream_t stream) {
    const float* text  = (const float*)d_in[0];
    const float* shape = (const float*)d_in[1];
    float* out = (float*)d_out;
    char* ws = (char*)d_ws;

    unsigned char* Xt = (unsigned char*)ws;
    unsigned char* Xm = (unsigned char*)(ws + 1u * 1024u * 1024u);
    float* R = (float*)(ws + 2u * 1024u * 1024u);

    convert_kernel<<<(B_ROWS * E_COLS / 4 + 255) / 256, 256, 0, stream>>>(
        text, shape, (unsigned*)Xt, (unsigned*)Xm, R, out);

    dim3 grid(NSTRIP, NHS, 2);                   // 128 strips x 7 splits x 2 layers
    gemm_rowsum_kernel<<<grid, 256, 0, stream>>>(Xt, Xm, R);

    finalize_kernel<<<256, 256, 0, stream>>>(text, shape, R, out);
}